// Round 1
// baseline (9632.876 us; speedup 1.0000x reference)
//
#include <hip/hip_runtime.h>
#include <math.h>

#define N_NODES 25000
#define N_EDGES 800000
#define IN_SZ 64
#define S_DIM 128
#define V_DIM 16
#define H_DIM 17
#define GVP_EPS 1e-8f
#define LN_EPS 1e-5f
#define INV_Z 0.1f

__device__ __forceinline__ float wave_sum(float x) {
#pragma unroll
  for (int off = 32; off; off >>= 1) x += __shfl_xor(x, off, 64);
  return x;
}

__device__ __forceinline__ float silu_f(float x) { return x / (1.0f + __expf(-x)); }

// ---------------------------------------------------------------- embed
// s = LN(silu(silu(h@W1+b1)@W2+b2)); v = 0
__global__ __launch_bounds__(128) void embed_kernel(
    const float* __restrict__ node_h,
    const float* __restrict__ W1, const float* __restrict__ b1,
    const float* __restrict__ W2, const float* __restrict__ b2,
    const float* __restrict__ g, const float* __restrict__ b,
    float* __restrict__ s, float* __restrict__ v) {
  const int n = blockIdx.x, tid = threadIdx.x;
  __shared__ float hb[IN_SZ];
  __shared__ float h1[S_DIM];
  __shared__ float red[4];
  if (tid < IN_SZ) hb[tid] = node_h[n * IN_SZ + tid];
  __syncthreads();
  float acc = b1[tid];
#pragma unroll 8
  for (int k = 0; k < IN_SZ; ++k) acc += hb[k] * W1[k * S_DIM + tid];
  float x = silu_f(acc);
  h1[tid] = x;
  __syncthreads();
  float acc2 = b2[tid];
#pragma unroll 8
  for (int k = 0; k < S_DIM; ++k) acc2 += h1[k] * W2[k * S_DIM + tid];
  float y = silu_f(acc2);
  // block LayerNorm over 128 (2 waves)
  const int wv = tid >> 6, lane = tid & 63;
  float sm = wave_sum(y);
  float sq = wave_sum(y * y);
  if (lane == 0) { red[wv] = sm; red[2 + wv] = sq; }
  __syncthreads();
  float tot = red[0] + red[1], tot2 = red[2] + red[3];
  float mu = tot * (1.0f / 128.0f);
  float var = tot2 * (1.0f / 128.0f) - mu * mu;
  float inv = rsqrtf(var + LN_EPS);
  s[n * S_DIM + tid] = (y - mu) * inv * g[tid] + b[tid];
  if (tid < 48) v[n * 48 + tid] = 0.0f;
}

// ---------------------------------------------------------------- edge message
// one wave per edge; 4 edges per 256-thread block
__global__ __launch_bounds__(256) void edge_msg_kernel(
    const float* __restrict__ s, const float* __restrict__ v,
    const float* __restrict__ coords,
    const int* __restrict__ esrc, const int* __restrict__ edst,
    float* __restrict__ smsg, float* __restrict__ vmsg,
    const float* __restrict__ Wh, const float* __restrict__ Wu,
    const float* __restrict__ Ws, const float* __restrict__ bs,
    const float* __restrict__ Wg, const float* __restrict__ bg,
    const float* __restrict__ lng, const float* __restrict__ lnb) {
  const int wv = threadIdx.x >> 6, lane = threadIdx.x & 63;
  const int e = blockIdx.x * 4 + wv;  // E divisible by 4, no tail
  const int src = esrc[e], dst = edst[e];

  __shared__ float z[4][148];   // [0..127] s_e, [128..144] sh
  __shared__ float ve[4][51];   // v_e [17][3]
  __shared__ float vh[4][51];
  __shared__ float fe[4][128];
  __shared__ float ga[4][16];

  // stage 1: gather
  if (lane < 48) {
    ve[wv][3 + lane] = v[src * 48 + lane];
  } else if (lane < 51) {
    int c = lane - 48;
    ve[wv][c] = coords[src * 3 + c] - coords[dst * 3 + c];
  }
  z[wv][lane] = s[src * S_DIM + lane];
  z[wv][64 + lane] = s[src * S_DIM + 64 + lane];
  __syncthreads();

  // stage 2: vh[h][c] = sum_v ve[v][c] * Wh[v][h]
  if (lane < 51) {
    int h = lane / 3, c = lane - 3 * h;
    float a = 0.0f;
#pragma unroll
    for (int vv = 0; vv < H_DIM; ++vv) a += ve[wv][vv * 3 + c] * Wh[vv * H_DIM + h];
    vh[wv][lane] = a;
  }
  __syncthreads();

  // stage 3: sh + vu
  if (lane < H_DIM) {
    float a = vh[wv][lane * 3], b_ = vh[wv][lane * 3 + 1], c_ = vh[wv][lane * 3 + 2];
    z[wv][128 + lane] = sqrtf(a * a + b_ * b_ + c_ * c_ + GVP_EPS);
  }
  float vur = 0.0f;
  if (lane < 48) {
    int u = lane / 3, c = lane - 3 * u;
#pragma unroll
    for (int h = 0; h < H_DIM; ++h) vur += vh[wv][h * 3 + c] * Wu[h * V_DIM + u];
  }
  __syncthreads();

  // stage 4: feats = silu(z[145] @ Ws + bs); each lane owns cols lane, lane+64
  float f0 = bs[lane], f1 = bs[64 + lane];
#pragma unroll 4
  for (int k = 0; k < 145; ++k) {
    float zz = z[wv][k];
    f0 += zz * Ws[k * S_DIM + lane];
    f1 += zz * Ws[k * S_DIM + 64 + lane];
  }
  f0 = silu_f(f0); f1 = silu_f(f1);
  fe[wv][lane] = f0; fe[wv][64 + lane] = f1;
  __syncthreads();

  // stage 5: gate (16 outs, 4 lanes each) + scalar-LN message atomics
  {
    int u = lane >> 2, q = lane & 3;
    float p = 0.0f;
#pragma unroll 8
    for (int k = q * 32; k < q * 32 + 32; ++k) p += fe[wv][k] * Wg[k * V_DIM + u];
    p += __shfl_xor(p, 1, 64);
    p += __shfl_xor(p, 2, 64);
    if (q == 0) ga[wv][u] = silu_f(p + bg[u]);
  }
  float sm = wave_sum(f0 + f1);
  float sq = wave_sum(f0 * f0 + f1 * f1);
  float mu = sm * (1.0f / 128.0f), var = sq * (1.0f / 128.0f) - mu * mu;
  float inv = rsqrtf(var + LN_EPS);
  atomicAdd(&smsg[dst * S_DIM + lane], ((f0 - mu) * inv * lng[lane] + lnb[lane]) * INV_Z);
  atomicAdd(&smsg[dst * S_DIM + 64 + lane], ((f1 - mu) * inv * lng[64 + lane] + lnb[64 + lane]) * INV_Z);
  __syncthreads();

  // stage 6: vector message: v_out = vu*gate, then vec_ln, scatter
  float vo = 0.0f;
  if (lane < 48) { int u = lane / 3; vo = vur * ga[wv][u]; }
  float n2 = wave_sum(vo * vo);
  float rms = sqrtf(n2 * (1.0f / 16.0f) + GVP_EPS);
  if (lane < 48) atomicAdd(&vmsg[dst * 48 + lane], vo / rms * INV_Z);
}

// ---------------------------------------------------------------- node update
__global__ __launch_bounds__(256) void node_update_kernel(
    float* __restrict__ s, float* __restrict__ v,
    const float* __restrict__ smsg, const float* __restrict__ vmsg,
    const float* __restrict__ Wh, const float* __restrict__ Wu,
    const float* __restrict__ Ws, const float* __restrict__ bs,
    const float* __restrict__ Wg, const float* __restrict__ bg,
    const float* __restrict__ lng, const float* __restrict__ lnb,
    const float* __restrict__ og, const float* __restrict__ ob) {
  const int wv = threadIdx.x >> 6, lane = threadIdx.x & 63;
  const int n = blockIdx.x * 4 + wv;  // N divisible by 4

  __shared__ float z[4][146];
  __shared__ float vel[4][48];
  __shared__ float vhl[4][48];
  __shared__ float fe[4][128];
  __shared__ float ga[4][16];

  // stage 1: s = LN(s + smsg); v = vec_ln(v + vmsg)
  float s0 = s[n * S_DIM + lane] + smsg[n * S_DIM + lane];
  float s1 = s[n * S_DIM + 64 + lane] + smsg[n * S_DIM + 64 + lane];
  float sm_ = wave_sum(s0 + s1), sq_ = wave_sum(s0 * s0 + s1 * s1);
  float mu = sm_ * (1.0f / 128.0f), var = sq_ * (1.0f / 128.0f) - mu * mu;
  float inv = rsqrtf(var + LN_EPS);
  float sa0 = (s0 - mu) * inv * og[lane] + ob[lane];
  float sa1 = (s1 - mu) * inv * og[64 + lane] + ob[64 + lane];
  z[wv][lane] = sa0; z[wv][64 + lane] = sa1;
  float vvr = 0.0f;
  if (lane < 48) vvr = v[n * 48 + lane] + vmsg[n * 48 + lane];
  float n2 = wave_sum(vvr * vvr);
  float rms = sqrtf(n2 * (1.0f / 16.0f) + GVP_EPS);
  float vln = vvr / rms;
  if (lane < 48) vel[wv][lane] = vln;
  __syncthreads();

  // stage 2: vh
  if (lane < 48) {
    int h = lane / 3, c = lane - 3 * h;
    float a = 0.0f;
#pragma unroll
    for (int vv = 0; vv < V_DIM; ++vv) a += vel[wv][vv * 3 + c] * Wh[vv * V_DIM + h];
    vhl[wv][lane] = a;
  }
  __syncthreads();

  // stage 3: sh + vu
  if (lane < V_DIM) {
    float a = vhl[wv][lane * 3], b_ = vhl[wv][lane * 3 + 1], c_ = vhl[wv][lane * 3 + 2];
    z[wv][128 + lane] = sqrtf(a * a + b_ * b_ + c_ * c_ + GVP_EPS);
  }
  float vur = 0.0f;
  if (lane < 48) {
    int u = lane / 3, c = lane - 3 * u;
#pragma unroll
    for (int h = 0; h < V_DIM; ++h) vur += vhl[wv][h * 3 + c] * Wu[h * V_DIM + u];
  }
  __syncthreads();

  // stage 4: feats over 144 inputs
  float f0 = bs[lane], f1 = bs[64 + lane];
#pragma unroll 4
  for (int k = 0; k < 144; ++k) {
    float zz = z[wv][k];
    f0 += zz * Ws[k * S_DIM + lane];
    f1 += zz * Ws[k * S_DIM + 64 + lane];
  }
  f0 = silu_f(f0); f1 = silu_f(f1);
  fe[wv][lane] = f0; fe[wv][64 + lane] = f1;
  __syncthreads();

  // stage 5: gate + scalar path (sr, residual, final LN, store s)
  {
    int u = lane >> 2, q = lane & 3;
    float p = 0.0f;
#pragma unroll 8
    for (int k = q * 32; k < q * 32 + 32; ++k) p += fe[wv][k] * Wg[k * V_DIM + u];
    p += __shfl_xor(p, 1, 64);
    p += __shfl_xor(p, 2, 64);
    if (q == 0) ga[wv][u] = silu_f(p + bg[u]);
  }
  float sm2 = wave_sum(f0 + f1), sq2 = wave_sum(f0 * f0 + f1 * f1);
  float mu2 = sm2 * (1.0f / 128.0f), var2 = sq2 * (1.0f / 128.0f) - mu2 * mu2;
  float inv2 = rsqrtf(var2 + LN_EPS);
  float t0 = sa0 + (f0 - mu2) * inv2 * lng[lane] + lnb[lane];
  float t1 = sa1 + (f1 - mu2) * inv2 * lng[64 + lane] + lnb[64 + lane];
  float sm3 = wave_sum(t0 + t1), sq3 = wave_sum(t0 * t0 + t1 * t1);
  float mu3 = sm3 * (1.0f / 128.0f), var3 = sq3 * (1.0f / 128.0f) - mu3 * mu3;
  float inv3 = rsqrtf(var3 + LN_EPS);
  s[n * S_DIM + lane] = (t0 - mu3) * inv3 * og[lane] + ob[lane];
  s[n * S_DIM + 64 + lane] = (t1 - mu3) * inv3 * og[64 + lane] + ob[64 + lane];
  __syncthreads();

  // stage 6: vector path: vr = vec_ln(vu*gate); v = vec_ln(vln + vr)
  float vo = 0.0f;
  if (lane < 48) { int u = lane / 3; vo = vur * ga[wv][u]; }
  float n22 = wave_sum(vo * vo);
  float rms2 = sqrtf(n22 * (1.0f / 16.0f) + GVP_EPS);
  float vr = vo / rms2;
  float v2 = (lane < 48) ? (vln + vr) : 0.0f;
  float n23 = wave_sum(v2 * v2);
  float rms3 = sqrtf(n23 * (1.0f / 16.0f) + GVP_EPS);
  if (lane < 48) v[n * 48 + lane] = v2 / rms3;
}

// ---------------------------------------------------------------- launch
extern "C" void kernel_launch(void* const* d_in, const int* in_sizes, int n_in,
                              void* d_out, int out_size, void* d_ws, size_t ws_size,
                              hipStream_t stream) {
  const float* node_h = (const float*)d_in[0];
  const float* coords = (const float*)d_in[1];
  const int* esrc = (const int*)d_in[2];
  const int* edst = (const int*)d_in[3];
  const float* emb_W1 = (const float*)d_in[4];
  const float* emb_b1 = (const float*)d_in[5];
  const float* emb_W2 = (const float*)d_in[6];
  const float* emb_b2 = (const float*)d_in[7];
  const float* norm_g = (const float*)d_in[8];
  const float* norm_b = (const float*)d_in[9];
  const float* em_Wh = (const float*)d_in[10];
  const float* em_Wu = (const float*)d_in[11];
  const float* em_Ws = (const float*)d_in[12];
  const float* em_bs = (const float*)d_in[13];
  const float* em_Wg = (const float*)d_in[14];
  const float* em_bg = (const float*)d_in[15];
  const float* em_lng = (const float*)d_in[16];
  const float* em_lnb = (const float*)d_in[17];
  const float* nu_Wh = (const float*)d_in[18];
  const float* nu_Wu = (const float*)d_in[19];
  const float* nu_Ws = (const float*)d_in[20];
  const float* nu_bs = (const float*)d_in[21];
  const float* nu_Wg = (const float*)d_in[22];
  const float* nu_bg = (const float*)d_in[23];
  const float* nu_lng = (const float*)d_in[24];
  const float* nu_lnb = (const float*)d_in[25];
  const float* ln_g = (const float*)d_in[26];
  const float* ln_b = (const float*)d_in[27];

  float* s = (float*)d_out;                  // [N,128] -> final output 0
  float* v = s + (size_t)N_NODES * S_DIM;    // [N,16,3] -> final output 1
  float* smsg = (float*)d_ws;                // [N,128]
  float* vmsg = smsg + (size_t)N_NODES * S_DIM;  // [N,48]

  embed_kernel<<<N_NODES, 128, 0, stream>>>(node_h, emb_W1, emb_b1, emb_W2, emb_b2,
                                            norm_g, norm_b, s, v);
  for (int i = 0; i < 3; ++i) {
    hipMemsetAsync(d_ws, 0, (size_t)N_NODES * 176 * sizeof(float), stream);
    edge_msg_kernel<<<N_EDGES / 4, 256, 0, stream>>>(
        s, v, coords, esrc, edst, smsg, vmsg,
        em_Wh + i * H_DIM * H_DIM, em_Wu + i * H_DIM * V_DIM,
        em_Ws + i * 145 * S_DIM, em_bs + i * S_DIM,
        em_Wg + i * S_DIM * V_DIM, em_bg + i * V_DIM,
        em_lng + i * S_DIM, em_lnb + i * S_DIM);
    node_update_kernel<<<N_NODES / 4, 256, 0, stream>>>(
        s, v, smsg, vmsg,
        nu_Wh + i * V_DIM * V_DIM, nu_Wu + i * V_DIM * V_DIM,
        nu_Ws + i * 144 * S_DIM, nu_bs + i * S_DIM,
        nu_Wg + i * S_DIM * V_DIM, nu_bg + i * V_DIM,
        nu_lng + i * S_DIM, nu_lnb + i * S_DIM,
        ln_g + i * S_DIM, ln_b + i * S_DIM);
  }
}

// Round 6
// 5003.601 us; speedup vs baseline: 1.9252x; 1.9252x over previous
//
#include <hip/hip_runtime.h>
#include <math.h>

#define N_NODES 25000
#define N_EDGES 800000
#define IN_SZ 64
#define S_DIM 128
#define V_DIM 16
#define H_DIM 17
#define GVP_EPS 1e-8f
#define LN_EPS 1e-5f
#define INV_Z 0.1f
#define TE 64  // edges per block in edge_gemm

// ---- LDS layout for edge_gemm (float offsets) ----
#define VE_O 0      // [64][52] v_e (coords diff + v)   (P1)  | VM overlay (P3)
#define VH_O 3328   // [64][52] vh                       (P1)  | SM overlay starts here (P3)
#define SH_O 6656   // [64][17] sh                       (P1->P2)
#define ZL_O 7744   // [64][17] z chunk                  (P2)
#define VU_O 8832   // [64][48] vu                       (P1->P3)
#define WSC_O 11904 // [17][128] Ws chunk / [128][16] Wg
#define WHL_O 14080 // 289 Wh
#define WUL_O 14369 // 272 Wu
#define ST_O 14641  // int[64] src tile
#define DT_O 14705  // int[64] dst tile
#define LDS_F 14769
#define VM_O 0
#define SM_O 3328

__device__ __forceinline__ float wave_sum(float x) {
#pragma unroll
  for (int off = 32; off; off >>= 1) x += __shfl_xor(x, off, 64);
  return x;
}

__device__ __forceinline__ float silu_f(float x) { return x / (1.0f + __expf(-x)); }

// reduce 16 partials across a 16-lane group; lane l16 gets total of index l16
__device__ __forceinline__ float reduce_scatter16(const float pu[16], int l16) {
  float r8[8];
#pragma unroll
  for (int u = 0; u < 8; ++u) {
    const float keep = (l16 & 8) ? pu[u + 8] : pu[u];
    const float send = (l16 & 8) ? pu[u] : pu[u + 8];
    r8[u] = keep + __shfl_xor(send, 8, 64);
  }
  float r4[4];
#pragma unroll
  for (int u = 0; u < 4; ++u) {
    const float keep = (l16 & 4) ? r8[u + 4] : r8[u];
    const float send = (l16 & 4) ? r8[u] : r8[u + 4];
    r4[u] = keep + __shfl_xor(send, 4, 64);
  }
  float r2[2];
#pragma unroll
  for (int u = 0; u < 2; ++u) {
    const float keep = (l16 & 2) ? r4[u + 2] : r4[u];
    const float send = (l16 & 2) ? r4[u] : r4[u + 2];
    r2[u] = keep + __shfl_xor(send, 2, 64);
  }
  const float keep = (l16 & 1) ? r2[1] : r2[0];
  const float send = (l16 & 1) ? r2[0] : r2[1];
  return keep + __shfl_xor(send, 1, 64);
}

// ---------------------------------------------------------------- embed
__global__ __launch_bounds__(128) void embed_kernel(
    const float* __restrict__ node_h,
    const float* __restrict__ W1, const float* __restrict__ b1,
    const float* __restrict__ W2, const float* __restrict__ b2,
    const float* __restrict__ g, const float* __restrict__ b,
    float* __restrict__ s, float* __restrict__ v) {
  const int n = blockIdx.x, tid = threadIdx.x;
  __shared__ float hb[IN_SZ];
  __shared__ float h1[S_DIM];
  __shared__ float red[4];
  if (tid < IN_SZ) hb[tid] = node_h[n * IN_SZ + tid];
  __syncthreads();
  float acc = b1[tid];
#pragma unroll 8
  for (int k = 0; k < IN_SZ; ++k) acc += hb[k] * W1[k * S_DIM + tid];
  float x = silu_f(acc);
  h1[tid] = x;
  __syncthreads();
  float acc2 = b2[tid];
#pragma unroll 8
  for (int k = 0; k < S_DIM; ++k) acc2 += h1[k] * W2[k * S_DIM + tid];
  float y = silu_f(acc2);
  const int wv = tid >> 6, lane = tid & 63;
  float sm = wave_sum(y);
  float sq = wave_sum(y * y);
  if (lane == 0) { red[wv] = sm; red[2 + wv] = sq; }
  __syncthreads();
  float tot = red[0] + red[1], tot2 = red[2] + red[3];
  float mu = tot * (1.0f / 128.0f);
  float var = tot2 * (1.0f / 128.0f) - mu * mu;
  float inv = rsqrtf(var + LN_EPS);
  s[n * S_DIM + tid] = (y - mu) * inv * g[tid] + b[tid];
  if (tid < 48) v[n * 48 + tid] = 0.0f;
}

// ---------------------------------------------------------------- sort infra
__global__ __launch_bounds__(256) void hist_kernel(const int* __restrict__ edst,
                                                   int* __restrict__ cnt) {
  int e = blockIdx.x * 256 + threadIdx.x;
  if (e < N_EDGES) atomicAdd(&cnt[edst[e]], 1);
}

__global__ __launch_bounds__(1024) void scan_kernel(const int* __restrict__ cnt,
                                                    int* __restrict__ rowptr) {
  __shared__ int wsum[16];
  __shared__ int carry_s;
  const int t = threadIdx.x, w = t >> 6, ln = t & 63;
  if (t == 0) carry_s = 0;
  __syncthreads();
  for (int base = 0; base < N_NODES; base += 1024) {
    const int idx = base + t;
    const int x = (idx < N_NODES) ? cnt[idx] : 0;
    int incl = x;
#pragma unroll
    for (int off = 1; off < 64; off <<= 1) {
      const int y = __shfl_up(incl, off, 64);
      if (ln >= off) incl += y;
    }
    if (ln == 63) wsum[w] = incl;
    __syncthreads();
    int woff = 0;
    for (int k = 0; k < w; ++k) woff += wsum[k];
    const int carry = carry_s;
    if (idx < N_NODES) rowptr[idx] = carry + woff + incl - x;
    __syncthreads();
    if (t == 1023) carry_s = carry + woff + incl;
    __syncthreads();
  }
  if (threadIdx.x == 0) rowptr[N_NODES] = carry_s;
}

__global__ __launch_bounds__(256) void initcur_kernel(const int* __restrict__ rowptr,
                                                      int* __restrict__ cursor) {
  int i = blockIdx.x * 256 + threadIdx.x;
  if (i < N_NODES) cursor[i] = rowptr[i];
}

__global__ __launch_bounds__(256) void scatter_kernel(const int* __restrict__ esrc,
                                                      const int* __restrict__ edst,
                                                      int* __restrict__ cursor,
                                                      int* __restrict__ srcs,
                                                      int* __restrict__ dsts) {
  int e = blockIdx.x * 256 + threadIdx.x;
  if (e < N_EDGES) {
    const int d = edst[e];
    const int p = atomicAdd(&cursor[d], 1);
    srcs[p] = esrc[e];
    dsts[p] = d;
  }
}

// ---------------------------------------------------------------- edge GEMM
// 64 edges per 256-thread block (dst-sorted when scratch allows).
// thread tile: eg = t>>4 owns edges eg*4..eg*4+3; cols (t&15)*8..+7
__global__ __launch_bounds__(256) void edge_gemm_kernel(
    const float* __restrict__ s, const float* __restrict__ v,
    const float* __restrict__ coords,
    const int* __restrict__ srcs, const int* __restrict__ dsts,
    float* __restrict__ smsg, float* __restrict__ vmsg,
    const float* __restrict__ Wh, const float* __restrict__ Wu,
    const float* __restrict__ Ws, const float* __restrict__ bs,
    const float* __restrict__ Wg, const float* __restrict__ bg,
    const float* __restrict__ lng, const float* __restrict__ lnb) {
  __shared__ float L[LDS_F];
  const int t = threadIdx.x;
  const int wv = t >> 6, ln = t & 63;
  const int eg = t >> 4, l16 = t & 15;
  const int e0 = blockIdx.x * TE;
  int* stile = (int*)&L[ST_O];
  int* dtile = (int*)&L[DT_O];
  if (t < TE) { stile[t] = srcs[e0 + t]; dtile[t] = dsts[e0 + t]; }
  for (int k = t; k < H_DIM * H_DIM; k += 256) L[WHL_O + k] = Wh[k];
  for (int k = t; k < H_DIM * V_DIM; k += 256) L[WUL_O + k] = Wu[k];
  __syncthreads();

  // P1a: gather v_e = [x_diff, v[src]] for this wave's 16 edges
  for (int i = 0; i < 16; ++i) {
    const int e = wv * 16 + i;
    const int src = stile[e];
    if (ln < 48) {
      L[VE_O + e * 52 + 3 + ln] = v[(size_t)src * 48 + ln];
    } else if (ln < 51) {
      const int c = ln - 48;
      L[VE_O + e * 52 + c] = coords[src * 3 + c] - coords[dtile[e] * 3 + c];
    }
  }
  __syncthreads();
  // P1b: vh = Wh^T applied over channels
  for (int i = 0; i < 16; ++i) {
    const int e = wv * 16 + i;
    if (ln < 51) {
      const int h = ln / 3, c = ln - 3 * h;
      float a = 0.0f;
#pragma unroll
      for (int vv = 0; vv < H_DIM; ++vv)
        a += L[VE_O + e * 52 + vv * 3 + c] * L[WHL_O + vv * H_DIM + h];
      L[VH_O + e * 52 + ln] = a;
    }
  }
  __syncthreads();
  // P1c: sh = |vh| rows
  for (int i = 0; i < 16; ++i) {
    const int e = wv * 16 + i;
    if (ln < H_DIM) {
      const float a = L[VH_O + e * 52 + ln * 3];
      const float b = L[VH_O + e * 52 + ln * 3 + 1];
      const float c = L[VH_O + e * 52 + ln * 3 + 2];
      L[SH_O + e * 17 + ln] = sqrtf(a * a + b * b + c * c + GVP_EPS);
    }
  }
  __syncthreads();
  // P1d: vu
  for (int i = 0; i < 16; ++i) {
    const int e = wv * 16 + i;
    if (ln < 48) {
      const int u = ln / 3, c = ln - 3 * u;
      float a = 0.0f;
#pragma unroll
      for (int h = 0; h < H_DIM; ++h)
        a += L[VH_O + e * 52 + h * 3 + c] * L[WUL_O + h * V_DIM + u];
      L[VU_O + e * 48 + ln] = a;
    }
  }

  // P2: feats GEMM  z[145] @ Ws[145][128]
  float acc[4][8];
  {
    const float4 b0 = *(const float4*)&bs[l16 * 8];
    const float4 b1 = *(const float4*)&bs[l16 * 8 + 4];
#pragma unroll
    for (int i = 0; i < 4; ++i) {
      acc[i][0] = b0.x; acc[i][1] = b0.y; acc[i][2] = b0.z; acc[i][3] = b0.w;
      acc[i][4] = b1.x; acc[i][5] = b1.y; acc[i][6] = b1.z; acc[i][7] = b1.w;
    }
  }
  for (int kc = 0; kc < 9; ++kc) {
    __syncthreads();
    {  // stage Ws rows kc*16..+15 (and row 144 on last chunk)
      const int r = t >> 4, ccol = (t & 15) * 8;
      const float* gsrc = &Ws[(size_t)(kc * 16 + r) * S_DIM + ccol];
      const float4 a0 = *(const float4*)gsrc;
      const float4 a1 = *(const float4*)(gsrc + 4);
      *(float4*)&L[WSC_O + r * 128 + ccol] = a0;
      *(float4*)&L[WSC_O + r * 128 + ccol + 4] = a1;
      if (kc == 8 && t < 128) L[WSC_O + 16 * 128 + t] = Ws[144 * S_DIM + t];
    }
    {  // stage z chunk
      const int e = t >> 2, q = t & 3;
      if (kc < 8) {
        const float4 zz = *(const float4*)&s[(size_t)stile[e] * S_DIM + kc * 16 + q * 4];
        L[ZL_O + e * 17 + q * 4 + 0] = zz.x;
        L[ZL_O + e * 17 + q * 4 + 1] = zz.y;
        L[ZL_O + e * 17 + q * 4 + 2] = zz.z;
        L[ZL_O + e * 17 + q * 4 + 3] = zz.w;
      } else {
#pragma unroll
        for (int j = 0; j < 4; ++j)
          L[ZL_O + e * 17 + q * 4 + j] = L[SH_O + e * 17 + q * 4 + j];
      }
    }
    __syncthreads();
#pragma unroll 4
    for (int kk = 0; kk < 16; ++kk) {
      const float4 w0 = *(const float4*)&L[WSC_O + kk * 128 + l16 * 8];
      const float4 w1 = *(const float4*)&L[WSC_O + kk * 128 + l16 * 8 + 4];
#pragma unroll
      for (int i = 0; i < 4; ++i) {
        const float z = L[ZL_O + (eg * 4 + i) * 17 + kk];
        acc[i][0] += z * w0.x; acc[i][1] += z * w0.y;
        acc[i][2] += z * w0.z; acc[i][3] += z * w0.w;
        acc[i][4] += z * w1.x; acc[i][5] += z * w1.y;
        acc[i][6] += z * w1.z; acc[i][7] += z * w1.w;
      }
    }
  }
  {  // k = 144 tail (z = sh[e][16], Ws row staged at WSC row 16)
    const float4 w0 = *(const float4*)&L[WSC_O + 16 * 128 + l16 * 8];
    const float4 w1 = *(const float4*)&L[WSC_O + 16 * 128 + l16 * 8 + 4];
#pragma unroll
    for (int i = 0; i < 4; ++i) {
      const float z = L[SH_O + (eg * 4 + i) * 17 + 16];
      acc[i][0] += z * w0.x; acc[i][1] += z * w0.y;
      acc[i][2] += z * w0.z; acc[i][3] += z * w0.w;
      acc[i][4] += z * w1.x; acc[i][5] += z * w1.y;
      acc[i][6] += z * w1.z; acc[i][7] += z * w1.w;
    }
  }
  __syncthreads();
  {  // stage Wg [128][16] into WSC
    const float4 g0 = *(const float4*)&Wg[t * 8];
    const float4 g1 = *(const float4*)&Wg[t * 8 + 4];
    *(float4*)&L[WSC_O + t * 8] = g0;
    *(float4*)&L[WSC_O + t * 8 + 4] = g1;
  }
  __syncthreads();
  // silu -> feats
#pragma unroll
  for (int i = 0; i < 4; ++i)
#pragma unroll
    for (int j = 0; j < 8; ++j) acc[i][j] = silu_f(acc[i][j]);

  // P3a: gate (2 edge-pairs), P3b: vector message into VM overlay
  const float bgv = bg[l16];
  float gate_i[4];
#pragma unroll
  for (int pr = 0; pr < 2; ++pr) {
    float puA[16], puB[16];
#pragma unroll
    for (int u = 0; u < 16; ++u) { puA[u] = 0.0f; puB[u] = 0.0f; }
#pragma unroll
    for (int j = 0; j < 8; ++j) {
      const int row = (l16 * 8 + j) * 16;
      const float4 w0 = *(const float4*)&L[WSC_O + row + 0];
      const float4 w1 = *(const float4*)&L[WSC_O + row + 4];
      const float4 w2 = *(const float4*)&L[WSC_O + row + 8];
      const float4 w3 = *(const float4*)&L[WSC_O + row + 12];
      const float fA = acc[pr * 2][j], fB = acc[pr * 2 + 1][j];
      puA[0] += fA * w0.x; puA[1] += fA * w0.y; puA[2] += fA * w0.z; puA[3] += fA * w0.w;
      puA[4] += fA * w1.x; puA[5] += fA * w1.y; puA[6] += fA * w1.z; puA[7] += fA * w1.w;
      puA[8] += fA * w2.x; puA[9] += fA * w2.y; puA[10] += fA * w2.z; puA[11] += fA * w2.w;
      puA[12] += fA * w3.x; puA[13] += fA * w3.y; puA[14] += fA * w3.z; puA[15] += fA * w3.w;
      puB[0] += fB * w0.x; puB[1] += fB * w0.y; puB[2] += fB * w0.z; puB[3] += fB * w0.w;
      puB[4] += fB * w1.x; puB[5] += fB * w1.y; puB[6] += fB * w1.z; puB[7] += fB * w1.w;
      puB[8] += fB * w2.x; puB[9] += fB * w2.y; puB[10] += fB * w2.z; puB[11] += fB * w2.w;
      puB[12] += fB * w3.x; puB[13] += fB * w3.y; puB[14] += fB * w3.z; puB[15] += fB * w3.w;
    }
    gate_i[pr * 2] = silu_f(reduce_scatter16(puA, l16) + bgv);
    gate_i[pr * 2 + 1] = silu_f(reduce_scatter16(puB, l16) + bgv);
  }
  // vector message: vm = vec_ln(vu * gate) * INV_Z  (VM overlays VE; VE dead)
#pragma unroll
  for (int i = 0; i < 4; ++i) {
    const int e = eg * 4 + i;
    const float g = gate_i[i];
    const float vm0 = L[VU_O + e * 48 + l16 * 3 + 0] * g;
    const float vm1 = L[VU_O + e * 48 + l16 * 3 + 1] * g;
    const float vm2 = L[VU_O + e * 48 + l16 * 3 + 2] * g;
    float ss = vm0 * vm0 + vm1 * vm1 + vm2 * vm2;
#pragma unroll
    for (int off = 1; off < 16; off <<= 1) ss += __shfl_xor(ss, off, 64);
    const float sc = INV_Z * rsqrtf(ss * (1.0f / 16.0f) + GVP_EPS);
    L[VM_O + e * 48 + l16 * 3 + 0] = vm0 * sc;
    L[VM_O + e * 48 + l16 * 3 + 1] = vm1 * sc;
    L[VM_O + e * 48 + l16 * 3 + 2] = vm2 * sc;
  }
  __syncthreads();  // VU fully consumed; SM may now overlay VH..VU

  // P3c: scalar message = LN(feats)*lng+lnb scaled, into SM overlay
  const float4 lg0 = *(const float4*)&lng[l16 * 8];
  const float4 lg1 = *(const float4*)&lng[l16 * 8 + 4];
  const float4 lb0 = *(const float4*)&lnb[l16 * 8];
  const float4 lb1 = *(const float4*)&lnb[l16 * 8 + 4];
#pragma unroll
  for (int i = 0; i < 4; ++i) {
    float s1 = 0.0f, s2 = 0.0f;
#pragma unroll
    for (int j = 0; j < 8; ++j) { s1 += acc[i][j]; s2 += acc[i][j] * acc[i][j]; }
#pragma unroll
    for (int off = 1; off < 16; off <<= 1) {
      s1 += __shfl_xor(s1, off, 64);
      s2 += __shfl_xor(s2, off, 64);
    }
    const float mu = s1 * (1.0f / 128.0f);
    const float var = s2 * (1.0f / 128.0f) - mu * mu;
    const float inv = rsqrtf(var + LN_EPS);
    const int e = eg * 4 + i;
    float4 o0, o1;
    o0.x = ((acc[i][0] - mu) * inv * lg0.x + lb0.x) * INV_Z;
    o0.y = ((acc[i][1] - mu) * inv * lg0.y + lb0.y) * INV_Z;
    o0.z = ((acc[i][2] - mu) * inv * lg0.z + lb0.z) * INV_Z;
    o0.w = ((acc[i][3] - mu) * inv * lg0.w + lb0.w) * INV_Z;
    o1.x = ((acc[i][4] - mu) * inv * lg1.x + lb1.x) * INV_Z;
    o1.y = ((acc[i][5] - mu) * inv * lg1.y + lb1.y) * INV_Z;
    o1.z = ((acc[i][6] - mu) * inv * lg1.z + lb1.z) * INV_Z;
    o1.w = ((acc[i][7] - mu) * inv * lg1.w + lb1.w) * INV_Z;
    *(float4*)&L[SM_O + e * 128 + l16 * 8] = o0;
    *(float4*)&L[SM_O + e * 128 + l16 * 8 + 4] = o1;
  }
  __syncthreads();

  // P4: per-dst-run aggregation, one atomic per (run, component)
  int r = 0;
  while (r < TE) {
    const int d = dtile[r];
    int rend = r + 1;
    while (rend < TE && dtile[rend] == d) ++rend;
    if (t < 128) {
      float a = 0.0f;
      for (int i = r; i < rend; ++i) a += L[SM_O + i * 128 + t];
      atomicAdd(&smsg[(size_t)d * S_DIM + t], a);
    } else if (t < 176) {
      const int c = t - 128;
      float a = 0.0f;
      for (int i = r; i < rend; ++i) a += L[VM_O + i * 48 + c];
      atomicAdd(&vmsg[(size_t)d * 48 + c], a);
    }
    r = rend;
  }
}

// ---------------------------------------------------------------- node update
__global__ __launch_bounds__(256) void node_update_kernel(
    float* __restrict__ s, float* __restrict__ v,
    const float* __restrict__ smsg, const float* __restrict__ vmsg,
    const float* __restrict__ Wh, const float* __restrict__ Wu,
    const float* __restrict__ Ws, const float* __restrict__ bs,
    const float* __restrict__ Wg, const float* __restrict__ bg,
    const float* __restrict__ lng, const float* __restrict__ lnb,
    const float* __restrict__ og, const float* __restrict__ ob) {
  const int wv = threadIdx.x >> 6, lane = threadIdx.x & 63;
  const int n = blockIdx.x * 4 + wv;

  __shared__ float z[4][146];
  __shared__ float vel[4][48];
  __shared__ float vhl[4][48];
  __shared__ float fe[4][128];
  __shared__ float ga[4][16];

  float s0 = s[n * S_DIM + lane] + smsg[n * S_DIM + lane];
  float s1 = s[n * S_DIM + 64 + lane] + smsg[n * S_DIM + 64 + lane];
  float sm_ = wave_sum(s0 + s1), sq_ = wave_sum(s0 * s0 + s1 * s1);
  float mu = sm_ * (1.0f / 128.0f), var = sq_ * (1.0f / 128.0f) - mu * mu;
  float inv = rsqrtf(var + LN_EPS);
  float sa0 = (s0 - mu) * inv * og[lane] + ob[lane];
  float sa1 = (s1 - mu) * inv * og[64 + lane] + ob[64 + lane];
  z[wv][lane] = sa0; z[wv][64 + lane] = sa1;
  float vvr = 0.0f;
  if (lane < 48) vvr = v[n * 48 + lane] + vmsg[n * 48 + lane];
  float n2 = wave_sum(vvr * vvr);
  float rms = sqrtf(n2 * (1.0f / 16.0f) + GVP_EPS);
  float vln = vvr / rms;
  if (lane < 48) vel[wv][lane] = vln;
  __syncthreads();

  if (lane < 48) {
    int h = lane / 3, c = lane - 3 * h;
    float a = 0.0f;
#pragma unroll
    for (int vv = 0; vv < V_DIM; ++vv) a += vel[wv][vv * 3 + c] * Wh[vv * V_DIM + h];
    vhl[wv][lane] = a;
  }
  __syncthreads();

  if (lane < V_DIM) {
    float a = vhl[wv][lane * 3], b_ = vhl[wv][lane * 3 + 1], c_ = vhl[wv][lane * 3 + 2];
    z[wv][128 + lane] = sqrtf(a * a + b_ * b_ + c_ * c_ + GVP_EPS);
  }
  float vur = 0.0f;
  if (lane < 48) {
    int u = lane / 3, c = lane - 3 * u;
#pragma unroll
    for (int h = 0; h < V_DIM; ++h) vur += vhl[wv][h * 3 + c] * Wu[h * V_DIM + u];
  }
  __syncthreads();

  float f0 = bs[lane], f1 = bs[64 + lane];
#pragma unroll 4
  for (int k = 0; k < 144; ++k) {
    float zz = z[wv][k];
    f0 += zz * Ws[k * S_DIM + lane];
    f1 += zz * Ws[k * S_DIM + 64 + lane];
  }
  f0 = silu_f(f0); f1 = silu_f(f1);
  fe[wv][lane] = f0; fe[wv][64 + lane] = f1;
  __syncthreads();

  {
    int u = lane >> 2, q = lane & 3;
    float p = 0.0f;
#pragma unroll 8
    for (int k = q * 32; k < q * 32 + 32; ++k) p += fe[wv][k] * Wg[k * V_DIM + u];
    p += __shfl_xor(p, 1, 64);
    p += __shfl_xor(p, 2, 64);
    if (q == 0) ga[wv][u] = silu_f(p + bg[u]);
  }
  float sm2 = wave_sum(f0 + f1), sq2 = wave_sum(f0 * f0 + f1 * f1);
  float mu2 = sm2 * (1.0f / 128.0f), var2 = sq2 * (1.0f / 128.0f) - mu2 * mu2;
  float inv2 = rsqrtf(var2 + LN_EPS);
  float t0 = sa0 + (f0 - mu2) * inv2 * lng[lane] + lnb[lane];
  float t1 = sa1 + (f1 - mu2) * inv2 * lng[64 + lane] + lnb[64 + lane];
  float sm3 = wave_sum(t0 + t1), sq3 = wave_sum(t0 * t0 + t1 * t1);
  float mu3 = sm3 * (1.0f / 128.0f), var3 = sq3 * (1.0f / 128.0f) - mu3 * mu3;
  float inv3 = rsqrtf(var3 + LN_EPS);
  s[n * S_DIM + lane] = (t0 - mu3) * inv3 * og[lane] + ob[lane];
  s[n * S_DIM + 64 + lane] = (t1 - mu3) * inv3 * og[64 + lane] + ob[64 + lane];
  __syncthreads();

  float vo = 0.0f;
  if (lane < 48) { int u = lane / 3; vo = vur * ga[wv][u]; }
  float n22 = wave_sum(vo * vo);
  float rms2 = sqrtf(n22 * (1.0f / 16.0f) + GVP_EPS);
  float vr = vo / rms2;
  float v2 = (lane < 48) ? (vln + vr) : 0.0f;
  float n23 = wave_sum(v2 * v2);
  float rms3 = sqrtf(n23 * (1.0f / 16.0f) + GVP_EPS);
  if (lane < 48) v[n * 48 + lane] = v2 / rms3;
}

// ---------------------------------------------------------------- launch
extern "C" void kernel_launch(void* const* d_in, const int* in_sizes, int n_in,
                              void* d_out, int out_size, void* d_ws, size_t ws_size,
                              hipStream_t stream) {
  const float* node_h = (const float*)d_in[0];
  const float* coords = (const float*)d_in[1];
  const int* esrc = (const int*)d_in[2];
  const int* edst = (const int*)d_in[3];
  const float* emb_W1 = (const float*)d_in[4];
  const float* emb_b1 = (const float*)d_in[5];
  const float* emb_W2 = (const float*)d_in[6];
  const float* emb_b2 = (const float*)d_in[7];
  const float* norm_g = (const float*)d_in[8];
  const float* norm_b = (const float*)d_in[9];
  const float* em_Wh = (const float*)d_in[10];
  const float* em_Wu = (const float*)d_in[11];
  const float* em_Ws = (const float*)d_in[12];
  const float* em_bs = (const float*)d_in[13];
  const float* em_Wg = (const float*)d_in[14];
  const float* em_bg = (const float*)d_in[15];
  const float* em_lng = (const float*)d_in[16];
  const float* em_lnb = (const float*)d_in[17];
  const float* nu_Wh = (const float*)d_in[18];
  const float* nu_Wu = (const float*)d_in[19];
  const float* nu_Ws = (const float*)d_in[20];
  const float* nu_bs = (const float*)d_in[21];
  const float* nu_Wg = (const float*)d_in[22];
  const float* nu_bg = (const float*)d_in[23];
  const float* nu_lng = (const float*)d_in[24];
  const float* nu_lnb = (const float*)d_in[25];
  const float* ln_g = (const float*)d_in[26];
  const float* ln_b = (const float*)d_in[27];

  float* s = (float*)d_out;                      // [N,128] output 0
  float* v = s + (size_t)N_NODES * S_DIM;        // [N,16,3] output 1

  float* smsg = (float*)d_ws;                    // [N,128]
  float* vmsg = smsg + (size_t)N_NODES * S_DIM;  // [N,48]
  int* rowptr = (int*)(vmsg + (size_t)N_NODES * 48);  // [N+1] (+pad)
  int* srcs = rowptr + N_NODES + 8;              // [E]
  int* dsts = srcs + N_EDGES;                    // [E]
  int* cnt = (int*)smsg;                         // alias (setup phase only)
  int* cursor = cnt + N_NODES;                   // alias (setup phase only)

  // Scratch needed for the sorted path: msg buffers + rowptr + srcs + dsts.
  const size_t need_sorted =
      (size_t)N_NODES * 176 * sizeof(float) +
      (size_t)(N_NODES + 1 + 8) * sizeof(int) +
      (size_t)2 * N_EDGES * sizeof(int);
  // ws_size is fixed across calls -> branch is deterministic (graph-safe).
  const bool use_sorted = ws_size >= need_sorted;

  if (use_sorted) {
    // ---- dst-sort setup (edge list is a launch input; recomputed every call)
    hipMemsetAsync(cnt, 0, N_NODES * sizeof(int), stream);
    hist_kernel<<<(N_EDGES + 255) / 256, 256, 0, stream>>>(edst, cnt);
    scan_kernel<<<1, 1024, 0, stream>>>(cnt, rowptr);
    initcur_kernel<<<(N_NODES + 255) / 256, 256, 0, stream>>>(rowptr, cursor);
    scatter_kernel<<<(N_EDGES + 255) / 256, 256, 0, stream>>>(esrc, edst, cursor, srcs, dsts);
  }
  const int* esrc_use = use_sorted ? srcs : esrc;
  const int* edst_use = use_sorted ? dsts : edst;

  embed_kernel<<<N_NODES, 128, 0, stream>>>(node_h, emb_W1, emb_b1, emb_W2, emb_b2,
                                            norm_g, norm_b, s, v);
  for (int i = 0; i < 3; ++i) {
    hipMemsetAsync(smsg, 0, (size_t)N_NODES * 176 * sizeof(float), stream);
    edge_gemm_kernel<<<N_EDGES / TE, 256, 0, stream>>>(
        s, v, coords, esrc_use, edst_use, smsg, vmsg,
        em_Wh + i * H_DIM * H_DIM, em_Wu + i * H_DIM * V_DIM,
        em_Ws + i * 145 * S_DIM, em_bs + i * S_DIM,
        em_Wg + i * S_DIM * V_DIM, em_bg + i * V_DIM,
        em_lng + i * S_DIM, em_lnb + i * S_DIM);
    node_update_kernel<<<N_NODES / 4, 256, 0, stream>>>(
        s, v, smsg, vmsg,
        nu_Wh + i * V_DIM * V_DIM, nu_Wu + i * V_DIM * V_DIM,
        nu_Ws + i * 144 * S_DIM, nu_bs + i * S_DIM,
        nu_Wg + i * S_DIM * V_DIM, nu_bg + i * V_DIM,
        nu_lng + i * S_DIM, nu_lnb + i * S_DIM,
        ln_g + i * S_DIM, ln_b + i * S_DIM);
  }
}